// Round 7
// baseline (4110.422 us; speedup 1.0000x reference)
//
#include <hip/hip_runtime.h>

#define L_ 2
#define D_ 1024
#define H_ 16
#define FF_ 4096
#define E_ 8
#define S_ 1024
#define B_ 8
#define T_ (S_*B_)
#define TP_ 17408
#define NBLK_MAX 136
#define HALF_BLK 68

typedef _Float16 half8 __attribute__((ext_vector_type(8)));
typedef _Float16 half4_t __attribute__((ext_vector_type(4)));
typedef float f32x4 __attribute__((ext_vector_type(4)));

__device__ __forceinline__ f32x4 mfma16(half8 a, half8 b, f32x4 c) {
  return __builtin_amdgcn_mfma_f32_16x16x32_f16(a, b, c, 0, 0, 0);
}

struct hl2 { _Float16 h, l; };
__device__ __forceinline__ hl2 split2(float v) {
  hl2 r;
  r.h = (_Float16)v;
  r.l = (_Float16)(v - (float)r.h);
  return r;
}

// async global->LDS, 16B per lane; dest = wave-uniform base + lane*16
__device__ __forceinline__ void gll16(const _Float16* g, _Float16* l) {
  __builtin_amdgcn_global_load_lds(
      (const __attribute__((address_space(1))) unsigned int*)g,
      (__attribute__((address_space(3))) unsigned int*)l, 16, 0, 0);
}

// ---------------- GEMM: C[M,N] = A[M,K] @ B[N,K]^T + bias ----------------
// BOTH operands pre-split fp16 planes, staged via global_load_lds into
// fragment-ordered lane-linear LDS ([blk16][lane][8] halfs) - m97 structure.
// NPROD=3: hh+hl+lh (~fp32). NPROD=1: hh only (fp16).
// OUT: 0 = fp32 C; 1 = fp16 planes Ch+Cl; 2 = fp16 plane Ch only.
template<int NPROD, bool GATHER, bool MOE, bool RELU, int OUT>
__global__ __launch_bounds__(256, NPROD == 3 ? 3 : 4)
void gemm_qq(const _Float16* __restrict__ Ah, const _Float16* __restrict__ Al,
             const _Float16* __restrict__ Bh, const _Float16* __restrict__ Bl,
             const float* __restrict__ bias,
             float* __restrict__ C, _Float16* __restrict__ Ch,
             _Float16* __restrict__ Cl,
             int K, int N, long bExpStrideH, int biasExpStride,
             const int* __restrict__ gtok,
             const int* __restrict__ nblk,
             const unsigned char* __restrict__ blk_e, int mb0)
{
  const int mb = blockIdx.x, nb = blockIdx.y;
  const _Float16* Bhp = Bh;
  const _Float16* Blp = Bl;
  const float* biasp = bias;
  if constexpr (MOE) {
    if (mb0 + mb >= *nblk) return;
    const int e = blk_e[mb0 + mb];
    Bhp += (long)e * bExpStrideH;
    if constexpr (NPROD == 3) Blp += (long)e * bExpStrideH;
    biasp += (long)e * biasExpStride;
  }
  const int bcol = nb * 128;
  constexpr int PL = (NPROD == 3) ? 2 : 1;
  __shared__ __align__(16) _Float16 lds[PL*8192];   // A planes | B planes

  const int tid = threadIdx.x;
  const int lane = tid & 63, wid = tid >> 6;
  const int wr = wid >> 1, wc = wid & 1;

  // hoisted staging sources: PL*16 chunks (A PL*8, B PL*8), PERW per wave
  constexpr int PERW = PL * 4;
  const _Float16* src[PERW];
  unsigned dstoff[PERW];
#pragma unroll
  for (int i = 0; i < PERW; ++i) {
    const int ch = wid * PERW + i;
    const bool isB = ch >= PL*8;
    const int c2 = isB ? ch - PL*8 : ch;
    const int plane = c2 >> 3, blk = c2 & 7;
    const int rc = blk*16 + (lane & 15);
    const int kh = (lane >> 4) * 8;
    if (!isB) {
      long r;
      if constexpr (GATHER) r = gtok[(mb0 + mb)*128 + rc];
      else r = (long)mb*128 + rc;
      src[i] = (plane ? Al : Ah) + r*(long)K + kh;
      dstoff[i] = plane*4096 + blk*512;
    } else {
      src[i] = (plane ? Blp : Bhp) + (long)(bcol + rc)*K + kh;
      dstoff[i] = PL*4096 + plane*4096 + blk*512;
    }
  }

  f32x4 acc[4][4];
#pragma unroll
  for (int m = 0; m < 4; ++m)
#pragma unroll
    for (int n = 0; n < 4; ++n) acc[m][n] = (f32x4){0.f, 0.f, 0.f, 0.f};

  for (int k0 = 0; k0 < K; k0 += 32) {
    __syncthreads();
#pragma unroll
    for (int i = 0; i < PERW; ++i) gll16(src[i] + k0, lds + dstoff[i]);
    __syncthreads();
    half8 ahf[4], bhf[4], alf[4], blf[4];
#pragma unroll
    for (int m = 0; m < 4; ++m) {
      ahf[m] = *(const half8*)&lds[(wr*4 + m)*512 + lane*8];
      bhf[m] = *(const half8*)&lds[PL*4096 + (wc*4 + m)*512 + lane*8];
      if constexpr (NPROD == 3) {
        alf[m] = *(const half8*)&lds[4096 + (wr*4 + m)*512 + lane*8];
        blf[m] = *(const half8*)&lds[PL*4096 + 4096 + (wc*4 + m)*512 + lane*8];
      }
    }
#pragma unroll
    for (int m = 0; m < 4; ++m)
#pragma unroll
      for (int n = 0; n < 4; ++n) {
        if constexpr (NPROD == 3) {
          acc[m][n] = mfma16(alf[m], bhf[n], acc[m][n]);
          acc[m][n] = mfma16(ahf[m], blf[n], acc[m][n]);
        }
        acc[m][n] = mfma16(ahf[m], bhf[n], acc[m][n]);
      }
  }

  // ---- epilogue
  int cbase;
  if constexpr (MOE) cbase = (OUT != 0) ? mb*128 : (mb0 + mb)*128;
  else cbase = mb*128;
  const int fr = lane & 15;
  const int r0 = (lane >> 4) * 4;
#pragma unroll
  for (int m = 0; m < 4; ++m) {
    const int grow = cbase + wr*64 + m*16 + r0;
#pragma unroll
    for (int n = 0; n < 4; ++n) {
      const int gcol = bcol + wc*64 + n*16 + fr;
      const float bv = biasp[gcol];
#pragma unroll
      for (int r = 0; r < 4; ++r) {
        float v = acc[m][n][r] + bv;
        if constexpr (RELU) v = fmaxf(v, 0.f);
        const long idx = (long)(grow + r) * N + gcol;
        if constexpr (OUT == 0) {
          C[idx] = v;
        } else {
          hl2 s = split2(v);
          Ch[idx] = s.h;
          if constexpr (OUT == 1) Cl[idx] = s.l;
        }
      }
    }
  }
}

// ---------------- weight split: fp32 -> fp16 h/l planes ----------------
template<bool WL>
__global__ __launch_bounds__(256) void wsplit_kernel(const float* __restrict__ w,
    _Float16* __restrict__ wh, _Float16* __restrict__ wl)
{
  const long i = ((long)blockIdx.x * 256 + threadIdx.x) * 4;
  const float4 v = *(const float4*)&w[i];
  half4_t h, l;
  { hl2 s = split2(v.x); h[0]=s.h; l[0]=s.l; }
  { hl2 s = split2(v.y); h[1]=s.h; l[1]=s.l; }
  { hl2 s = split2(v.z); h[2]=s.h; l[2]=s.l; }
  { hl2 s = split2(v.w); h[3]=s.h; l[3]=s.l; }
  *(half4_t*)&wh[i] = h;
  if constexpr (WL) *(half4_t*)&wl[i] = l;
}

// ---------------- add-pos: writes (x+pos) planes and x planes ----------------
__global__ __launch_bounds__(256) void addpos_kernel(const float* __restrict__ x,
    const float* __restrict__ p,
    _Float16* __restrict__ XPh, _Float16* __restrict__ XPl,
    _Float16* __restrict__ XFh, _Float16* __restrict__ XFl)
{
  const long i = (long)blockIdx.x * 256 + threadIdx.x;
  const float4 a = ((const float4*)x)[i];
  const float4 b = ((const float4*)p)[i];
  half4_t fh, fl, ph, pl;
  { hl2 s = split2(a.x); fh[0]=s.h; fl[0]=s.l; }
  { hl2 s = split2(a.y); fh[1]=s.h; fl[1]=s.l; }
  { hl2 s = split2(a.z); fh[2]=s.h; fl[2]=s.l; }
  { hl2 s = split2(a.w); fh[3]=s.h; fl[3]=s.l; }
  { hl2 s = split2(a.x+b.x); ph[0]=s.h; pl[0]=s.l; }
  { hl2 s = split2(a.y+b.y); ph[1]=s.h; pl[1]=s.l; }
  { hl2 s = split2(a.z+b.z); ph[2]=s.h; pl[2]=s.l; }
  { hl2 s = split2(a.w+b.w); ph[3]=s.h; pl[3]=s.l; }
  *(half4_t*)&XFh[i*4] = fh; *(half4_t*)&XFl[i*4] = fl;
  *(half4_t*)&XPh[i*4] = ph; *(half4_t*)&XPl[i*4] = pl;
}

// ---------------- V transpose: [t][d] planes -> [bh*64+d][s] planes ----------
__global__ __launch_bounds__(256) void vtrans_kernel(
    const _Float16* __restrict__ Vh, const _Float16* __restrict__ Vl,
    _Float16* __restrict__ Vth, _Float16* __restrict__ Vtl)
{
  const int st = blockIdx.x, bh = blockIdx.y;
  const int b = bh >> 4, h = bh & 15;
  __shared__ __align__(16) _Float16 th[64*64];
  __shared__ __align__(16) _Float16 tl[64*64];
  const int tid = threadIdx.x;
#pragma unroll
  for (int i = 0; i < 2; ++i) {
    const int r = i*32 + (tid >> 3);
    const int c = tid & 7;
    const long t = (long)(st*64 + r)*8 + b;
    const long ga = t*1024 + h*64 + c*8;
    const int la = r*64 + ((c ^ (r & 7)) << 3);
    *(half8*)&th[la] = *(const half8*)&Vh[ga];
    *(half8*)&tl[la] = *(const half8*)&Vl[ga];
  }
  __syncthreads();
#pragma unroll
  for (int i = 0; i < 2; ++i) {
    const int d = i*32 + (tid >> 3);
    const int sc = tid & 7;
    half8 oh, ol;
#pragma unroll
    for (int j = 0; j < 8; ++j) {
      const int s = sc*8 + j;
      const int la = s*64 + (((d >> 3) ^ (s & 7)) << 3) + (d & 7);
      oh[j] = th[la]; ol[j] = tl[la];
    }
    const long oa = ((long)bh*64 + d)*1024 + st*64 + sc*8;
    *(half8*)&Vth[oa] = oh;
    *(half8*)&Vtl[oa] = ol;
  }
}

// ---------------- flash attention (all-fp16-plane, fixed-max softmax) --------
__global__ __launch_bounds__(256, 4) void attn_kernel(
    const _Float16* __restrict__ QKh, const _Float16* __restrict__ QKl,
    const _Float16* __restrict__ Vth, const _Float16* __restrict__ Vtl,
    _Float16* __restrict__ Oh, _Float16* __restrict__ Ol)
{
  const int qb = blockIdx.x;
  const int bh = blockIdx.y;
  const int b = bh >> 4, h = bh & 15;
  const int tid = threadIdx.x, lane = tid & 63, wid = tid >> 6;
  const int fr = lane & 15, fkc = lane >> 4;
  __shared__ __align__(16) _Float16 Kh_s[32*64];
  __shared__ __align__(16) _Float16 Kl_s[32*64];
  __shared__ __align__(16) _Float16 Ph[4][16*32];
  __shared__ __align__(16) _Float16 Pl[4][16*32];

  half8 qfh[2], qfl[2];
  {
    const long qbase = ((long)(qb*64 + wid*16 + fr)*8 + b)*2048 + h*64;
#pragma unroll
    for (int dc = 0; dc < 2; ++dc) {
      qfh[dc] = *(const half8*)&QKh[qbase + dc*32 + fkc*8];
      qfl[dc] = *(const half8*)&QKl[qbase + dc*32 + fkc*8];
    }
  }
  f32x4 oacc[4];
#pragma unroll
  for (int c = 0; c < 4; ++c) oacc[c] = (f32x4){0.f,0.f,0.f,0.f};
  float lsum[4] = {0.f,0.f,0.f,0.f};

  for (int kt = 0; kt < 32; ++kt) {
    __syncthreads();
#pragma unroll
    for (int ch = wid; ch < 8; ch += 4) {
      const int pl = ch >> 2, qt = ch & 3;
      const int r = qt*8 + (lane >> 3), c = lane & 7;
      const long t = (long)(kt*32 + r)*8 + b;
      const _Float16* srcp = (pl ? QKl : QKh) + t*2048 + 1024 + h*64 + ((c ^ (r & 7)) << 3);
      _Float16* dstp = (pl ? Kl_s : Kh_s) + (qt << 9);
      gll16(srcp, dstp);
    }
    __syncthreads();

    f32x4 st[2];
    st[0] = (f32x4){0.f,0.f,0.f,0.f}; st[1] = (f32x4){0.f,0.f,0.f,0.f};
#pragma unroll
    for (int tc = 0; tc < 2; ++tc)
#pragma unroll
      for (int dc = 0; dc < 2; ++dc) {
        const int kr = tc*16 + fr;
        const int cc = ((dc*4 + fkc) ^ (kr & 7)) << 3;
        const half8 kfh = *(const half8*)&Kh_s[kr*64 + cc];
        const half8 kfl = *(const half8*)&Kl_s[kr*64 + cc];
        st[tc] = mfma16(qfl[dc], kfh, st[tc]);
        st[tc] = mfma16(qfh[dc], kfl, st[tc]);
        st[tc] = mfma16(qfh[dc], kfh, st[tc]);
      }

    float p0[4], p1[4];
#pragma unroll
    for (int r = 0; r < 4; ++r) {
      p0[r] = __expf(st[0][r] * 0.125f);
      p1[r] = __expf(st[1][r] * 0.125f);
      lsum[r] += p0[r] + p1[r];
    }

#pragma unroll
    for (int r = 0; r < 4; ++r) {
      const int prow = fkc*4 + r;
      hl2 s0 = split2(p0[r]);
      hl2 s1 = split2(p1[r]);
      const int i0 = prow*32 + (((fr>>3) ^ (prow&3)) << 3) + (fr & 7);
      const int c1 = fr + 16;
      const int i1 = prow*32 + (((c1>>3) ^ (prow&3)) << 3) + (c1 & 7);
      Ph[wid][i0] = s0.h;  Pl[wid][i0] = s0.l;
      Ph[wid][i1] = s1.h;  Pl[wid][i1] = s1.l;
    }
    const int ip = fr*32 + ((fkc ^ (fr&3)) << 3);
    const half8 pfh = *(const half8*)&Ph[wid][ip];
    const half8 pfl = *(const half8*)&Pl[wid][ip];

    const long vtb = ((long)bh*64)*1024 + kt*32 + fkc*8;
#pragma unroll
    for (int c = 0; c < 4; ++c) {
      const long va = vtb + (long)(c*16 + fr)*1024;
      const half8 vfh = *(const half8*)&Vth[va];
      const half8 vfl = *(const half8*)&Vtl[va];
      oacc[c] = mfma16(pfl, vfh, oacc[c]);
      oacc[c] = mfma16(pfh, vfl, oacc[c]);
      oacc[c] = mfma16(pfh, vfh, oacc[c]);
    }
  }
#pragma unroll
  for (int r = 0; r < 4; ++r) {
    float l = lsum[r];
    l += __shfl_xor(l, 1); l += __shfl_xor(l, 2);
    l += __shfl_xor(l, 4); l += __shfl_xor(l, 8);
    lsum[r] = l;
  }
#pragma unroll
  for (int c = 0; c < 4; ++c)
#pragma unroll
    for (int r = 0; r < 4; ++r) {
      const int srow = qb*64 + wid*16 + fkc*4 + r;
      const long idx = ((long)srow * B_ + b) * 1024 + h*64 + c*16 + fr;
      hl2 s = split2(oacc[c][r] / lsum[r]);
      Oh[idx] = s.h; Ol[idx] = s.l;
    }
}

// ---------------- fused residual + LayerNorm (+ optional planes) ----------------
template<bool PLANES>
__global__ __launch_bounds__(256) void ln_kernel(
    const float* __restrict__ a, const float* __restrict__ b,
    const float* __restrict__ w, const float* __restrict__ bias,
    float* __restrict__ out, _Float16* __restrict__ Lh, _Float16* __restrict__ Ll)
{
  const int row = blockIdx.x, tid = threadIdx.x;
  const long base = (long)row * D_;
  const float4 va = *(const float4*)&a[base + tid*4];
  const float4 vb = *(const float4*)&b[base + tid*4];
  const float x0 = va.x+vb.x, x1 = va.y+vb.y, x2 = va.z+vb.z, x3 = va.w+vb.w;
  float s = (x0+x1)+(x2+x3);
  float q = (x0*x0+x1*x1)+(x2*x2+x3*x3);
  for (int m = 1; m < 64; m <<= 1) { s += __shfl_xor(s, m); q += __shfl_xor(q, m); }
  __shared__ float rs[4], rq[4];
  const int wid = tid >> 6;
  if ((tid & 63) == 0) { rs[wid] = s; rq[wid] = q; }
  __syncthreads();
  s = (rs[0]+rs[1])+(rs[2]+rs[3]);
  q = (rq[0]+rq[1])+(rq[2]+rq[3]);
  const float mean = s * (1.f/D_);
  const float var = q * (1.f/D_) - mean*mean;
  const float inv = rsqrtf(var + 1e-5f);
  const float4 vw = *(const float4*)&w[tid*4];
  const float4 vbi = *(const float4*)&bias[tid*4];
  float4 r;
  r.x = (x0-mean)*inv*vw.x + vbi.x;
  r.y = (x1-mean)*inv*vw.y + vbi.y;
  r.z = (x2-mean)*inv*vw.z + vbi.z;
  r.w = (x3-mean)*inv*vw.w + vbi.w;
  *(float4*)&out[base + tid*4] = r;
  if constexpr (PLANES) {
    half4_t hh, ll;
    { hl2 t = split2(r.x); hh[0]=t.h; ll[0]=t.l; }
    { hl2 t = split2(r.y); hh[1]=t.h; ll[1]=t.l; }
    { hl2 t = split2(r.z); hh[2]=t.h; ll[2]=t.l; }
    { hl2 t = split2(r.w); hh[3]=t.h; ll[3]=t.l; }
    *(half4_t*)&Lh[base + tid*4] = hh;
    *(half4_t*)&Ll[base + tid*4] = ll;
  }
}

// ---------------- MoE gate (fp32) ----------------
__global__ __launch_bounds__(256) void gate_kernel(const float* __restrict__ x,
    const float* __restrict__ gw, const float* __restrict__ gb, float* __restrict__ sc)
{
  const int t = blockIdx.x * 32 + (threadIdx.x >> 3);
  const int e = threadIdx.x & 7;
  const float* xr = x + (long)t * D_;
  const float* wr = gw + (long)e * D_;
  float a0 = 0, a1 = 0, a2 = 0, a3 = 0;
  for (int d = 0; d < D_; d += 4) {
    const float4 av = *(const float4*)&xr[d];
    const float4 wv = *(const float4*)&wr[d];
    a0 += av.x*wv.x; a1 += av.y*wv.y; a2 += av.z*wv.z; a3 += av.w*wv.w;
  }
  sc[t*E_ + e] = (a0+a1)+(a2+a3) + gb[e];
}

__global__ __launch_bounds__(256) void topk_kernel(const float* __restrict__ sc,
    int* __restrict__ topi, float* __restrict__ tkwt, int* __restrict__ cnt)
{
  const int t = blockIdx.x * 256 + threadIdx.x;
  const float* r = sc + (long)t * E_;
  float v1 = -1e30f, v2 = -1e30f; int i1 = 0, i2 = 0;
#pragma unroll
  for (int e = 0; e < E_; ++e) {
    const float v = r[e];
    if (v > v1) { v2 = v1; i2 = i1; v1 = v; i1 = e; }
    else if (v > v2) { v2 = v; i2 = e; }
  }
  const float e2 = expf(v2 - v1);
  const float inv = 1.f / (1.f + e2);
  topi[t*2] = i1; topi[t*2+1] = i2;
  tkwt[t*2] = inv; tkwt[t*2+1] = e2 * inv;
  atomicAdd(&cnt[i1], 1); atomicAdd(&cnt[i2], 1);
}

__global__ void plan_kernel(const int* __restrict__ cnt, int* __restrict__ cursor,
    int* __restrict__ nblk, unsigned char* __restrict__ blk_e, int* __restrict__ pairs_tok)
{
  __shared__ int soff[9];
  __shared__ int scnt[8];
  if (threadIdx.x == 0) {
    int o = 0;
#pragma unroll
    for (int e = 0; e < E_; ++e) {
      soff[e] = o; cursor[e] = o; scnt[e] = cnt[e];
      o += (cnt[e] + 127) & ~127;
    }
    soff[8] = o;
    *nblk = o >> 7;
  }
  __syncthreads();
  const int total = soff[8];
  for (int bidx = threadIdx.x; bidx < (total >> 7); bidx += 256) {
    const int rb = bidx << 7;
    int e = 0;
    while (e < 7 && rb >= soff[e+1]) ++e;
    blk_e[bidx] = (unsigned char)e;
  }
#pragma unroll
  for (int e = 0; e < E_; ++e) {
    const int s0 = soff[e] + scnt[e], s1 = soff[e+1];
    for (int i = s0 + (int)threadIdx.x; i < s1; i += 256) pairs_tok[i] = 0;
  }
}

__global__ __launch_bounds__(256) void fill_kernel(const int* __restrict__ topi,
    int* __restrict__ cursor, int* __restrict__ pairs_tok, int* __restrict__ tkpos)
{
  const int t = blockIdx.x * 256 + threadIdx.x;
#pragma unroll
  for (int k = 0; k < 2; ++k) {
    const int e = topi[t*2+k];
    const int pos = atomicAdd(&cursor[e], 1);
    pairs_tok[pos] = t;
    tkpos[t*2+k] = pos;
  }
}

__global__ __launch_bounds__(256) void combine_kernel(const float* __restrict__ y,
    const int* __restrict__ tkpos, const float* __restrict__ tkwt, float* __restrict__ out)
{
  const int t = blockIdx.x, d = threadIdx.x * 4;
  const long p0 = tkpos[t*2], p1 = tkpos[t*2+1];
  const float w0 = tkwt[t*2], w1 = tkwt[t*2+1];
  const float4 a = *(const float4*)&y[p0*D_ + d];
  const float4 b = *(const float4*)&y[p1*D_ + d];
  float4 r;
  r.x = w0*a.x + w1*b.x; r.y = w0*a.y + w1*b.y;
  r.z = w0*a.z + w1*b.z; r.w = w0*a.w + w1*b.w;
  *(float4*)&out[(long)t*D_ + d] = r;
}

__global__ void aux_kernel(const int* __restrict__ topi, const float* __restrict__ tkwt,
    float* __restrict__ aux_out, int first)
{
  float u[8] = {0,0,0,0,0,0,0,0};
  for (int i = threadIdx.x; i < T_*2; i += 256) {
    const int e = topi[i]; const float wv = tkwt[i];
#pragma unroll
    for (int k = 0; k < 8; ++k) u[k] += (e == k) ? wv : 0.f;
  }
  __shared__ float red[256];
  float usage[8];
#pragma unroll
  for (int e = 0; e < 8; ++e) {
    red[threadIdx.x] = u[e];
    __syncthreads();
    for (int s = 128; s > 0; s >>= 1) {
      if ((int)threadIdx.x < s) red[threadIdx.x] += red[threadIdx.x + s];
      __syncthreads();
    }
    usage[e] = red[0];
    __syncthreads();
  }
  if (threadIdx.x == 0) {
    float sum = 0;
#pragma unroll
    for (int e = 0; e < 8; ++e) sum += usage[e];
    float Hh = 0;
#pragma unroll
    for (int e = 0; e < 8; ++e) {
      const float p = usage[e] / sum;
      Hh -= p * logf(p + 1e-9f);
    }
    if (first) *aux_out = 0.5f * Hh;
    else *aux_out += 0.5f * Hh;
  }
}

// ---------------- launcher ----------------
extern "C" void kernel_launch(void* const* d_in, const int* in_sizes, int n_in,
                              void* d_out, int out_size, void* d_ws, size_t ws_size,
                              hipStream_t stream) {
  const float* src    = (const float*)d_in[0];
  const float* pos    = (const float*)d_in[1];
  const float* qkv_w  = (const float*)d_in[2];
  const float* qkv_b  = (const float*)d_in[3];
  const float* out_w  = (const float*)d_in[4];
  const float* out_b  = (const float*)d_in[5];
  const float* ln1_w  = (const float*)d_in[6];
  const float* ln1_b  = (const float*)d_in[7];
  const float* ln2_w  = (const float*)d_in[8];
  const float* ln2_b  = (const float*)d_in[9];
  const float* gate_w = (const float*)d_in[10];
  const float* gate_b = (const float*)d_in[11];
  const float* w1     = (const float*)d_in[12];
  const float* b1     = (const float*)d_in[13];
  const float* w2     = (const float*)d_in[14];
  const float* b2     = (const float*)d_in[15];
  float* out = (float*)d_out;

  char* ws = (char*)d_ws;
  size_t off = 0;
  auto alloc = [&](size_t bytes) -> char* {
    char* p = ws + off;
    off = (off + bytes + 255) & ~(size_t)255;
    return p;
  };
  const size_t TD = (size_t)T_ * D_;
  float* x_master = (float*)alloc(TD*4);
  float* ln1_f    = (float*)alloc(TD*4);
  float* moe_out  = (float*)alloc(TD*4);
  _Float16* L1h   = (_Float16*)alloc(TD*2);
  _Float16* L1l   = (_Float16*)alloc(TD*2);
  // dense weight planes (per layer)
  const size_t QW = (size_t)3*D_*D_;
  _Float16* DQh = (_Float16*)alloc(QW*2);
  _Float16* DQl = (_Float16*)alloc(QW*2);
  _Float16* DOh = (_Float16*)alloc((size_t)D_*D_*2);
  _Float16* DOl = (_Float16*)alloc((size_t)D_*D_*2);
  float* scores   = (float*)alloc((size_t)T_*E_*4);
  int*   topi     = (int*)alloc((size_t)T_*2*4);
  float* tkwt     = (float*)alloc((size_t)T_*2*4);
  int*   tkpos    = (int*)alloc((size_t)T_*2*4);
  int*   pairs_tok= (int*)alloc((size_t)TP_*4);
  int*   cnt      = (int*)alloc(E_*4);
  int*   cursor   = (int*)alloc(E_*4);
  int*   nblk     = (int*)alloc(256);
  unsigned char* blk_e = (unsigned char*)alloc(256);
  // union: attn (TD*24) vs moe (H planes + y + w1/w2 planes)
  const size_t attn_sz = TD*24;
  const size_t hrows = (size_t)HALF_BLK * 128;
  const size_t WE = (size_t)E_*FF_*D_;       // elems per-layer w1 (= w2)
  const size_t moe_sz = hrows*FF_*2*2 + (size_t)TP_*D_*4 + WE*2*4;
  char* uni = alloc(attn_sz > moe_sz ? attn_sz : moe_sz);
  // attn-phase views
  _Float16* QKh = (_Float16*)uni;
  _Float16* QKl = (_Float16*)(uni + TD*4);
  _Float16* Vh  = (_Float16*)(uni + TD*8);
  _Float16* Vl  = (_Float16*)(uni + TD*10);
  _Float16* Vth = (_Float16*)(uni + TD*12);
  _Float16* Vtl = (_Float16*)(uni + TD*14);
  _Float16* XPh = (_Float16*)(uni + TD*16);
  _Float16* XPl = (_Float16*)(uni + TD*18);
  _Float16* XFh = (_Float16*)(uni + TD*20);
  _Float16* XFl = (_Float16*)(uni + TD*22);
  _Float16* Oh  = XFh;
  _Float16* Ol  = XFl;
  // moe-phase views
  _Float16* Hh  = (_Float16*)uni;
  _Float16* Hl  = (_Float16*)(uni + hrows*FF_*2);
  float* y_buf  = (float*)(uni + hrows*FF_*4);
  _Float16* W1h = (_Float16*)(uni + hrows*FF_*4 + (size_t)TP_*D_*4);
  _Float16* W1l = W1h + WE;
  _Float16* W2h = W1l + WE;
  _Float16* W2l = W2h + WE;

  for (int l = 0; l < L_; ++l) {
    const float* x_f  = (l == 0) ? src : x_master;
    const float* qkvw = qkv_w + (size_t)l*3*D_*D_;
    const float* qkvb = qkv_b + (size_t)l*3*D_;
    const float* outw = out_w + (size_t)l*D_*D_;
    const float* outb = out_b + (size_t)l*D_;
    const float* w1l  = w1 + (size_t)l*WE;
    const float* b1l  = b1 + (size_t)l*E_*FF_;
    const float* w2l  = w2 + (size_t)l*WE;
    const float* b2l  = b2 + (size_t)l*E_*D_;

    // 0. dense weight planes
    wsplit_kernel<true><<<QW/1024, 256, 0, stream>>>(qkvw, DQh, DQl);
    wsplit_kernel<true><<<D_*D_/1024, 256, 0, stream>>>(outw, DOh, DOl);
    // 1. activation planes
    addpos_kernel<<<TD/1024, 256, 0, stream>>>(x_f, pos, XPh, XPl, XFh, XFl);
    // 2. [Q|K] planes = (x+pos) @ qkv_w[:2D]^T + b
    gemm_qq<3,false,false,false,1><<<dim3(T_/128, 16), 256, 0, stream>>>(
        XPh, XPl, DQh, DQl, qkvb, nullptr, QKh, QKl,
        D_, 2*D_, 0, 0, nullptr, nullptr, nullptr, 0);
    // 3. V planes = x @ qkv_w[2D:]^T + b
    gemm_qq<3,false,false,false,1><<<dim3(T_/128, 8), 256, 0, stream>>>(
        XFh, XFl, DQh + (size_t)2*D_*D_, DQl + (size_t)2*D_*D_, qkvb + 2*D_,
        nullptr, Vh, Vl, D_, D_, 0, 0, nullptr, nullptr, nullptr, 0);
    // 4. V transpose
    vtrans_kernel<<<dim3(16, 128), 256, 0, stream>>>(Vh, Vl, Vth, Vtl);
    // 5. flash attention -> O planes (overwrites XF)
    attn_kernel<<<dim3(16, 128), 256, 0, stream>>>(QKh, QKl, Vth, Vtl, Oh, Ol);
    // 6. proj = O @ out_w^T + b (into moe_out)
    gemm_qq<3,false,false,false,0><<<dim3(T_/128, 8), 256, 0, stream>>>(
        Oh, Ol, DOh, DOl, outb, moe_out, nullptr, nullptr,
        D_, D_, 0, 0, nullptr, nullptr, nullptr, 0);
    // 6b. MoE weight planes (after attn-phase buffers are dead)
    if (l == 0) {
      wsplit_kernel<true><<<WE/1024, 256, 0, stream>>>(w1l, W1h, W1l);
      wsplit_kernel<true><<<WE/1024, 256, 0, stream>>>(w2l, W2h, W2l);
    } else {
      wsplit_kernel<false><<<WE/1024, 256, 0, stream>>>(w1l, W1h, nullptr);
      wsplit_kernel<false><<<WE/1024, 256, 0, stream>>>(w2l, W2h, nullptr);
    }
    // 7. ln1 = LN(x + proj)
    ln_kernel<true><<<T_, 256, 0, stream>>>(x_f, moe_out, ln1_w + (size_t)l*D_,
        ln1_b + (size_t)l*D_, ln1_f, L1h, L1l);
    // 8-11. gate -> top2 -> plan -> fill
    gate_kernel<<<T_/32, 256, 0, stream>>>(ln1_f, gate_w + (size_t)l*E_*D_,
        gate_b + (size_t)l*E_, scores);
    (void)hipMemsetAsync(cnt, 0, E_*4, stream);
    topk_kernel<<<T_/256, 256, 0, stream>>>(scores, topi, tkwt, cnt);
    plan_kernel<<<1, 256, 0, stream>>>(cnt, cursor, nblk, blk_e, pairs_tok);
    fill_kernel<<<T_/256, 256, 0, stream>>>(topi, cursor, pairs_tok, tkpos);
    // 12-13. MoE FFN in two row-block halves
    for (int half = 0; half < 2; ++half) {
      const int mb0 = half * HALF_BLK;
      if (l == 0) {
        gemm_qq<3,true,true,true,1><<<dim3(HALF_BLK, FF_/128), 256, 0, stream>>>(
            L1h, L1l, W1h, W1l, b1l, nullptr, Hh, Hl,
            D_, FF_, (long)FF_*D_, FF_, pairs_tok, nblk, blk_e, mb0);
        gemm_qq<3,false,true,false,0><<<dim3(HALF_BLK, D_/128), 256, 0, stream>>>(
            Hh, Hl, W2h, W2l, b2l, y_buf, nullptr, nullptr,
            FF_, D_, (long)D_*FF_, D_, nullptr, nblk, blk_e, mb0);
      } else {
        gemm_qq<1,true,true,true,2><<<dim3(HALF_BLK, FF_/128), 256, 0, stream>>>(
            L1h, nullptr, W1h, nullptr, b1l, nullptr, Hh, nullptr,
            D_, FF_, (long)FF_*D_, FF_, pairs_tok, nblk, blk_e, mb0);
        gemm_qq<1,false,true,false,0><<<dim3(HALF_BLK, D_/128), 256, 0, stream>>>(
            Hh, nullptr, W2h, nullptr, b2l, y_buf, nullptr, nullptr,
            FF_, D_, (long)D_*FF_, D_, nullptr, nblk, blk_e, mb0);
      }
    }
    // 14. combine
    combine_kernel<<<T_, 256, 0, stream>>>(y_buf, tkpos, tkwt, moe_out);
    // 15. aux
    aux_kernel<<<1, 256, 0, stream>>>(topi, tkwt, out + TD, l == 0 ? 1 : 0);
    // 16. x = LN(ln1 + moe_out)
    float* ln2_dst = (l == L_-1) ? out : x_master;
    ln_kernel<false><<<T_, 256, 0, stream>>>(ln1_f, moe_out, ln2_w + (size_t)l*D_,
        ln2_b + (size_t)l*D_, ln2_dst, nullptr, nullptr);
  }
}

// Round 10
// 3956.827 us; speedup vs baseline: 1.0388x; 1.0388x over previous
//
#include <hip/hip_runtime.h>

#define L_ 2
#define D_ 1024
#define H_ 16
#define FF_ 4096
#define E_ 8
#define S_ 1024
#define B_ 8
#define T_ (S_*B_)
#define TP_ 17408
#define NBLK_MAX 136
#define HALF_BLK 68

typedef _Float16 half8 __attribute__((ext_vector_type(8)));
typedef _Float16 half4_t __attribute__((ext_vector_type(4)));
typedef float f32x4 __attribute__((ext_vector_type(4)));

__device__ __forceinline__ f32x4 mfma16(half8 a, half8 b, f32x4 c) {
  return __builtin_amdgcn_mfma_f32_16x16x32_f16(a, b, c, 0, 0, 0);
}

struct hl2 { _Float16 h, l; };
__device__ __forceinline__ hl2 split2(float v) {
  hl2 r;
  r.h = (_Float16)v;
  r.l = (_Float16)(v - (float)r.h);
  return r;
}

// async global->LDS, 16B per lane; dest = wave-uniform base + lane*16
__device__ __forceinline__ void gll16(const _Float16* g, _Float16* l) {
  __builtin_amdgcn_global_load_lds(
      (const __attribute__((address_space(1))) unsigned int*)g,
      (__attribute__((address_space(3))) unsigned int*)l, 16, 0, 0);
}

// XCD-aware bijective swizzle (T1): each XCD gets a contiguous chunk of
// logical tile ids. Requires nwg % 8 == 0 (true for all launches here).
// x-dim is the fast logical axis.
__device__ __forceinline__ void xcd_swz(int& xo, int& yo) {
  const int gx = gridDim.x;
  const int nwg = gx * gridDim.y;
  const int flat = blockIdx.y * gx + blockIdx.x;
  const int swz = (flat & 7) * (nwg >> 3) + (flat >> 3);
  xo = swz % gx;
  yo = swz / gx;
}

// ---------------- GEMM: C[M,N] = A[M,K] @ B[N,K]^T + bias ----------------
// BOTH operands pre-split fp16 planes, staged via global_load_lds into
// fragment-ordered lane-linear LDS ([blk16][lane][8] halfs) - m97 structure.
// NPROD=3: hh+hl+lh (~fp32). NPROD=1: hh only (fp16).
// OUT: 0 = fp32 C; 1 = fp16 planes Ch+Cl; 2 = fp16 plane Ch only.
template<int NPROD, bool GATHER, bool MOE, bool RELU, int OUT>
__global__ __launch_bounds__(256, NPROD == 3 ? 3 : 4)
void gemm_qq(const _Float16* __restrict__ Ah, const _Float16* __restrict__ Al,
             const _Float16* __restrict__ Bh, const _Float16* __restrict__ Bl,
             const float* __restrict__ bias,
             float* __restrict__ C, _Float16* __restrict__ Ch,
             _Float16* __restrict__ Cl,
             int K, int N, long bExpStrideH, int biasExpStride,
             const int* __restrict__ gtok,
             const int* __restrict__ nblk,
             const unsigned char* __restrict__ blk_e, int mb0)
{
  int mb, nb;
  xcd_swz(mb, nb);
  const _Float16* Bhp = Bh;
  const _Float16* Blp = Bl;
  const float* biasp = bias;
  if constexpr (MOE) {
    if (mb0 + mb >= *nblk) return;
    const int e = blk_e[mb0 + mb];
    Bhp += (long)e * bExpStrideH;
    if constexpr (NPROD == 3) Blp += (long)e * bExpStrideH;
    biasp += (long)e * biasExpStride;
  }
  const int bcol = nb * 128;
  constexpr int PL = (NPROD == 3) ? 2 : 1;
  __shared__ __align__(16) _Float16 lds[PL*8192];   // A planes | B planes

  const int tid = threadIdx.x;
  const int lane = tid & 63, wid = tid >> 6;
  const int wr = wid >> 1, wc = wid & 1;

  // hoisted staging sources: PL*16 chunks (A PL*8, B PL*8), PERW per wave
  constexpr int PERW = PL * 4;
  const _Float16* src[PERW];
  unsigned dstoff[PERW];
#pragma unroll
  for (int i = 0; i < PERW; ++i) {
    const int ch = wid * PERW + i;
    const bool isB = ch >= PL*8;
    const int c2 = isB ? ch - PL*8 : ch;
    const int plane = c2 >> 3, blk = c2 & 7;
    const int rc = blk*16 + (lane & 15);
    const int kh = (lane >> 4) * 8;
    if (!isB) {
      long r;
      if constexpr (GATHER) r = gtok[(mb0 + mb)*128 + rc];
      else r = (long)mb*128 + rc;
      src[i] = (plane ? Al : Ah) + r*(long)K + kh;
      dstoff[i] = plane*4096 + blk*512;
    } else {
      src[i] = (plane ? Blp : Bhp) + (long)(bcol + rc)*K + kh;
      dstoff[i] = PL*4096 + plane*4096 + blk*512;
    }
  }

  f32x4 acc[4][4];
#pragma unroll
  for (int m = 0; m < 4; ++m)
#pragma unroll
    for (int n = 0; n < 4; ++n) acc[m][n] = (f32x4){0.f, 0.f, 0.f, 0.f};

  for (int k0 = 0; k0 < K; k0 += 32) {
    __syncthreads();
#pragma unroll
    for (int i = 0; i < PERW; ++i) gll16(src[i] + k0, lds + dstoff[i]);
    __syncthreads();
    half8 ahf[4], bhf[4], alf[4], blf[4];
#pragma unroll
    for (int m = 0; m < 4; ++m) {
      ahf[m] = *(const half8*)&lds[(wr*4 + m)*512 + lane*8];
      bhf[m] = *(const half8*)&lds[PL*4096 + (wc*4 + m)*512 + lane*8];
      if constexpr (NPROD == 3) {
        alf[m] = *(const half8*)&lds[4096 + (wr*4 + m)*512 + lane*8];
        blf[m] = *(const half8*)&lds[PL*4096 + 4096 + (wc*4 + m)*512 + lane*8];
      }
    }
#pragma unroll
    for (int m = 0; m < 4; ++m)
#pragma unroll
      for (int n = 0; n < 4; ++n) {
        if constexpr (NPROD == 3) {
          acc[m][n] = mfma16(alf[m], bhf[n], acc[m][n]);
          acc[m][n] = mfma16(ahf[m], blf[n], acc[m][n]);
        }
        acc[m][n] = mfma16(ahf[m], bhf[n], acc[m][n]);
      }
  }

  // ---- epilogue
  int cbase;
  if constexpr (MOE) cbase = (OUT != 0) ? mb*128 : (mb0 + mb)*128;
  else cbase = mb*128;
  const int fr = lane & 15;
  const int r0 = (lane >> 4) * 4;
#pragma unroll
  for (int m = 0; m < 4; ++m) {
    const int grow = cbase + wr*64 + m*16 + r0;
#pragma unroll
    for (int n = 0; n < 4; ++n) {
      const int gcol = bcol + wc*64 + n*16 + fr;
      const float bv = biasp[gcol];
#pragma unroll
      for (int r = 0; r < 4; ++r) {
        float v = acc[m][n][r] + bv;
        if constexpr (RELU) v = fmaxf(v, 0.f);
        const long idx = (long)(grow + r) * N + gcol;
        if constexpr (OUT == 0) {
          C[idx] = v;
        } else {
          hl2 s = split2(v);
          Ch[idx] = s.h;
          if constexpr (OUT == 1) Cl[idx] = s.l;
        }
      }
    }
  }
}

// ---------------- weight split: fp32 -> fp16 h/l planes ----------------
template<bool WL>
__global__ __launch_bounds__(256) void wsplit_kernel(const float* __restrict__ w,
    _Float16* __restrict__ wh, _Float16* __restrict__ wl)
{
  const long i = ((long)blockIdx.x * 256 + threadIdx.x) * 4;
  const float4 v = *(const float4*)&w[i];
  half4_t h, l;
  { hl2 s = split2(v.x); h[0]=s.h; l[0]=s.l; }
  { hl2 s = split2(v.y); h[1]=s.h; l[1]=s.l; }
  { hl2 s = split2(v.z); h[2]=s.h; l[2]=s.l; }
  { hl2 s = split2(v.w); h[3]=s.h; l[3]=s.l; }
  *(half4_t*)&wh[i] = h;
  if constexpr (WL) *(half4_t*)&wl[i] = l;
}

// ---------------- add-pos: writes (x+pos) planes and x planes ----------------
__global__ __launch_bounds__(256) void addpos_kernel(const float* __restrict__ x,
    const float* __restrict__ p,
    _Float16* __restrict__ XPh, _Float16* __restrict__ XPl,
    _Float16* __restrict__ XFh, _Float16* __restrict__ XFl)
{
  const long i = (long)blockIdx.x * 256 + threadIdx.x;
  const float4 a = ((const float4*)x)[i];
  const float4 b = ((const float4*)p)[i];
  half4_t fh, fl, ph, pl;
  { hl2 s = split2(a.x); fh[0]=s.h; fl[0]=s.l; }
  { hl2 s = split2(a.y); fh[1]=s.h; fl[1]=s.l; }
  { hl2 s = split2(a.z); fh[2]=s.h; fl[2]=s.l; }
  { hl2 s = split2(a.w); fh[3]=s.h; fl[3]=s.l; }
  { hl2 s = split2(a.x+b.x); ph[0]=s.h; pl[0]=s.l; }
  { hl2 s = split2(a.y+b.y); ph[1]=s.h; pl[1]=s.l; }
  { hl2 s = split2(a.z+b.z); ph[2]=s.h; pl[2]=s.l; }
  { hl2 s = split2(a.w+b.w); ph[3]=s.h; pl[3]=s.l; }
  *(half4_t*)&XFh[i*4] = fh; *(half4_t*)&XFl[i*4] = fl;
  *(half4_t*)&XPh[i*4] = ph; *(half4_t*)&XPl[i*4] = pl;
}

// ---------------- V transpose: [t][d] planes -> [bh*64+d][s] planes ----------
__global__ __launch_bounds__(256) void vtrans_kernel(
    const _Float16* __restrict__ Vh, const _Float16* __restrict__ Vl,
    _Float16* __restrict__ Vth, _Float16* __restrict__ Vtl)
{
  const int st = blockIdx.x, bh = blockIdx.y;
  const int b = bh >> 4, h = bh & 15;
  __shared__ __align__(16) _Float16 th[64*64];
  __shared__ __align__(16) _Float16 tl[64*64];
  const int tid = threadIdx.x;
#pragma unroll
  for (int i = 0; i < 2; ++i) {
    const int r = i*32 + (tid >> 3);
    const int c = tid & 7;
    const long t = (long)(st*64 + r)*8 + b;
    const long ga = t*1024 + h*64 + c*8;
    const int la = r*64 + ((c ^ (r & 7)) << 3);
    *(half8*)&th[la] = *(const half8*)&Vh[ga];
    *(half8*)&tl[la] = *(const half8*)&Vl[ga];
  }
  __syncthreads();
#pragma unroll
  for (int i = 0; i < 2; ++i) {
    const int d = i*32 + (tid >> 3);
    const int sc = tid & 7;
    half8 oh, ol;
#pragma unroll
    for (int j = 0; j < 8; ++j) {
      const int s = sc*8 + j;
      const int la = s*64 + (((d >> 3) ^ (s & 7)) << 3) + (d & 7);
      oh[j] = th[la]; ol[j] = tl[la];
    }
    const long oa = ((long)bh*64 + d)*1024 + st*64 + sc*8;
    *(half8*)&Vth[oa] = oh;
    *(half8*)&Vtl[oa] = ol;
  }
}

// ---------------- flash attention (all-fp16-plane, fixed-max softmax) --------
__global__ __launch_bounds__(256, 4) void attn_kernel(
    const _Float16* __restrict__ QKh, const _Float16* __restrict__ QKl,
    const _Float16* __restrict__ Vth, const _Float16* __restrict__ Vtl,
    _Float16* __restrict__ Oh, _Float16* __restrict__ Ol)
{
  int qb, bh;
  xcd_swz(qb, bh);
  const int b = bh >> 4, h = bh & 15;
  const int tid = threadIdx.x, lane = tid & 63, wid = tid >> 6;
  const int fr = lane & 15, fkc = lane >> 4;
  __shared__ __align__(16) _Float16 Kh_s[32*64];
  __shared__ __align__(16) _Float16 Kl_s[32*64];
  __shared__ __align__(16) _Float16 Ph[4][16*32];
  __shared__ __align__(16) _Float16 Pl[4][16*32];

  half8 qfh[2], qfl[2];
  {
    const long qbase = ((long)(qb*64 + wid*16 + fr)*8 + b)*2048 + h*64;
#pragma unroll
    for (int dc = 0; dc < 2; ++dc) {
      qfh[dc] = *(const half8*)&QKh[qbase + dc*32 + fkc*8];
      qfl[dc] = *(const half8*)&QKl[qbase + dc*32 + fkc*8];
    }
  }
  f32x4 oacc[4];
#pragma unroll
  for (int c = 0; c < 4; ++c) oacc[c] = (f32x4){0.f,0.f,0.f,0.f};
  float lsum[4] = {0.f,0.f,0.f,0.f};

  for (int kt = 0; kt < 32; ++kt) {
    __syncthreads();
#pragma unroll
    for (int ch = wid; ch < 8; ch += 4) {
      const int pl = ch >> 2, qt = ch & 3;
      const int r = qt*8 + (lane >> 3), c = lane & 7;
      const long t = (long)(kt*32 + r)*8 + b;
      const _Float16* srcp = (pl ? QKl : QKh) + t*2048 + 1024 + h*64 + ((c ^ (r & 7)) << 3);
      _Float16* dstp = (pl ? Kl_s : Kh_s) + (qt << 9);
      gll16(srcp, dstp);
    }
    __syncthreads();

    f32x4 st[2];
    st[0] = (f32x4){0.f,0.f,0.f,0.f}; st[1] = (f32x4){0.f,0.f,0.f,0.f};
#pragma unroll
    for (int tc = 0; tc < 2; ++tc)
#pragma unroll
      for (int dc = 0; dc < 2; ++dc) {
        const int kr = tc*16 + fr;
        const int cc = ((dc*4 + fkc) ^ (kr & 7)) << 3;
        const half8 kfh = *(const half8*)&Kh_s[kr*64 + cc];
        const half8 kfl = *(const half8*)&Kl_s[kr*64 + cc];
        st[tc] = mfma16(qfl[dc], kfh, st[tc]);
        st[tc] = mfma16(qfh[dc], kfl, st[tc]);
        st[tc] = mfma16(qfh[dc], kfh, st[tc]);
      }

    float p0[4], p1[4];
#pragma unroll
    for (int r = 0; r < 4; ++r) {
      p0[r] = __expf(st[0][r] * 0.125f);
      p1[r] = __expf(st[1][r] * 0.125f);
      lsum[r] += p0[r] + p1[r];
    }

#pragma unroll
    for (int r = 0; r < 4; ++r) {
      const int prow = fkc*4 + r;
      hl2 s0 = split2(p0[r]);
      hl2 s1 = split2(p1[r]);
      const int i0 = prow*32 + (((fr>>3) ^ (prow&3)) << 3) + (fr & 7);
      const int c1 = fr + 16;
      const int i1 = prow*32 + (((c1>>3) ^ (prow&3)) << 3) + (c1 & 7);
      Ph[wid][i0] = s0.h;  Pl[wid][i0] = s0.l;
      Ph[wid][i1] = s1.h;  Pl[wid][i1] = s1.l;
    }
    const int ip = fr*32 + ((fkc ^ (fr&3)) << 3);
    const half8 pfh = *(const half8*)&Ph[wid][ip];
    const half8 pfl = *(const half8*)&Pl[wid][ip];

    const long vtb = ((long)bh*64)*1024 + kt*32 + fkc*8;
#pragma unroll
    for (int c = 0; c < 4; ++c) {
      const long va = vtb + (long)(c*16 + fr)*1024;
      const half8 vfh = *(const half8*)&Vth[va];
      const half8 vfl = *(const half8*)&Vtl[va];
      oacc[c] = mfma16(pfl, vfh, oacc[c]);
      oacc[c] = mfma16(pfh, vfl, oacc[c]);
      oacc[c] = mfma16(pfh, vfh, oacc[c]);
    }
  }
#pragma unroll
  for (int r = 0; r < 4; ++r) {
    float l = lsum[r];
    l += __shfl_xor(l, 1); l += __shfl_xor(l, 2);
    l += __shfl_xor(l, 4); l += __shfl_xor(l, 8);
    lsum[r] = l;
  }
#pragma unroll
  for (int c = 0; c < 4; ++c)
#pragma unroll
    for (int r = 0; r < 4; ++r) {
      const int srow = qb*64 + wid*16 + fkc*4 + r;
      const long idx = ((long)srow * B_ + b) * 1024 + h*64 + c*16 + fr;
      hl2 s = split2(oacc[c][r] / lsum[r]);
      Oh[idx] = s.h; Ol[idx] = s.l;
    }
}

// ---------------- fused residual + LayerNorm (+ optional planes) ----------------
template<bool PLANES>
__global__ __launch_bounds__(256) void ln_kernel(
    const float* __restrict__ a, const float* __restrict__ b,
    const float* __restrict__ w, const float* __restrict__ bias,
    float* __restrict__ out, _Float16* __restrict__ Lh, _Float16* __restrict__ Ll)
{
  const int row = blockIdx.x, tid = threadIdx.x;
  const long base = (long)row * D_;
  const float4 va = *(const float4*)&a[base + tid*4];
  const float4 vb = *(const float4*)&b[base + tid*4];
  const float x0 = va.x+vb.x, x1 = va.y+vb.y, x2 = va.z+vb.z, x3 = va.w+vb.w;
  float s = (x0+x1)+(x2+x3);
  float q = (x0*x0+x1*x1)+(x2*x2+x3*x3);
  for (int m = 1; m < 64; m <<= 1) { s += __shfl_xor(s, m); q += __shfl_xor(q, m); }
  __shared__ float rs[4], rq[4];
  const int wid = tid >> 6;
  if ((tid & 63) == 0) { rs[wid] = s; rq[wid] = q; }
  __syncthreads();
  s = (rs[0]+rs[1])+(rs[2]+rs[3]);
  q = (rq[0]+rq[1])+(rq[2]+rq[3]);
  const float mean = s * (1.f/D_);
  const float var = q * (1.f/D_) - mean*mean;
  const float inv = rsqrtf(var + 1e-5f);
  const float4 vw = *(const float4*)&w[tid*4];
  const float4 vbi = *(const float4*)&bias[tid*4];
  float4 r;
  r.x = (x0-mean)*inv*vw.x + vbi.x;
  r.y = (x1-mean)*inv*vw.y + vbi.y;
  r.z = (x2-mean)*inv*vw.z + vbi.z;
  r.w = (x3-mean)*inv*vw.w + vbi.w;
  *(float4*)&out[base + tid*4] = r;
  if constexpr (PLANES) {
    half4_t hh, ll;
    { hl2 t = split2(r.x); hh[0]=t.h; ll[0]=t.l; }
    { hl2 t = split2(r.y); hh[1]=t.h; ll[1]=t.l; }
    { hl2 t = split2(r.z); hh[2]=t.h; ll[2]=t.l; }
    { hl2 t = split2(r.w); hh[3]=t.h; ll[3]=t.l; }
    *(half4_t*)&Lh[base + tid*4] = hh;
    *(half4_t*)&Ll[base + tid*4] = ll;
  }
}

// ---------------- MoE gate (fp32) ----------------
__global__ __launch_bounds__(256) void gate_kernel(const float* __restrict__ x,
    const float* __restrict__ gw, const float* __restrict__ gb, float* __restrict__ sc)
{
  const int t = blockIdx.x * 32 + (threadIdx.x >> 3);
  const int e = threadIdx.x & 7;
  const float* xr = x + (long)t * D_;
  const float* wr = gw + (long)e * D_;
  float a0 = 0, a1 = 0, a2 = 0, a3 = 0;
  for (int d = 0; d < D_; d += 4) {
    const float4 av = *(const float4*)&xr[d];
    const float4 wv = *(const float4*)&wr[d];
    a0 += av.x*wv.x; a1 += av.y*wv.y; a2 += av.z*wv.z; a3 += av.w*wv.w;
  }
  sc[t*E_ + e] = (a0+a1)+(a2+a3) + gb[e];
}

__global__ __launch_bounds__(256) void topk_kernel(const float* __restrict__ sc,
    int* __restrict__ topi, float* __restrict__ tkwt, int* __restrict__ cnt)
{
  const int t = blockIdx.x * 256 + threadIdx.x;
  const float* r = sc + (long)t * E_;
  float v1 = -1e30f, v2 = -1e30f; int i1 = 0, i2 = 0;
#pragma unroll
  for (int e = 0; e < E_; ++e) {
    const float v = r[e];
    if (v > v1) { v2 = v1; i2 = i1; v1 = v; i1 = e; }
    else if (v > v2) { v2 = v; i2 = e; }
  }
  const float e2 = expf(v2 - v1);
  const float inv = 1.f / (1.f + e2);
  topi[t*2] = i1; topi[t*2+1] = i2;
  tkwt[t*2] = inv; tkwt[t*2+1] = e2 * inv;
  atomicAdd(&cnt[i1], 1); atomicAdd(&cnt[i2], 1);
}

__global__ void plan_kernel(const int* __restrict__ cnt, int* __restrict__ cursor,
    int* __restrict__ nblk, unsigned char* __restrict__ blk_e, int* __restrict__ pairs_tok)
{
  __shared__ int soff[9];
  __shared__ int scnt[8];
  if (threadIdx.x == 0) {
    int o = 0;
#pragma unroll
    for (int e = 0; e < E_; ++e) {
      soff[e] = o; cursor[e] = o; scnt[e] = cnt[e];
      o += (cnt[e] + 127) & ~127;
    }
    soff[8] = o;
    *nblk = o >> 7;
  }
  __syncthreads();
  const int total = soff[8];
  for (int bidx = threadIdx.x; bidx < (total >> 7); bidx += 256) {
    const int rb = bidx << 7;
    int e = 0;
    while (e < 7 && rb >= soff[e+1]) ++e;
    blk_e[bidx] = (unsigned char)e;
  }
#pragma unroll
  for (int e = 0; e < E_; ++e) {
    const int s0 = soff[e] + scnt[e], s1 = soff[e+1];
    for (int i = s0 + (int)threadIdx.x; i < s1; i += 256) pairs_tok[i] = 0;
  }
}

__global__ __launch_bounds__(256) void fill_kernel(const int* __restrict__ topi,
    int* __restrict__ cursor, int* __restrict__ pairs_tok, int* __restrict__ tkpos)
{
  const int t = blockIdx.x * 256 + threadIdx.x;
#pragma unroll
  for (int k = 0; k < 2; ++k) {
    const int e = topi[t*2+k];
    const int pos = atomicAdd(&cursor[e], 1);
    pairs_tok[pos] = t;
    tkpos[t*2+k] = pos;
  }
}

__global__ __launch_bounds__(256) void combine_kernel(const float* __restrict__ y,
    const int* __restrict__ tkpos, const float* __restrict__ tkwt, float* __restrict__ out)
{
  const int t = blockIdx.x, d = threadIdx.x * 4;
  const long p0 = tkpos[t*2], p1 = tkpos[t*2+1];
  const float w0 = tkwt[t*2], w1 = tkwt[t*2+1];
  const float4 a = *(const float4*)&y[p0*D_ + d];
  const float4 b = *(const float4*)&y[p1*D_ + d];
  float4 r;
  r.x = w0*a.x + w1*b.x; r.y = w0*a.y + w1*b.y;
  r.z = w0*a.z + w1*b.z; r.w = w0*a.w + w1*b.w;
  *(float4*)&out[(long)t*D_ + d] = r;
}

__global__ void aux_kernel(const int* __restrict__ topi, const float* __restrict__ tkwt,
    float* __restrict__ aux_out, int first)
{
  float u[8] = {0,0,0,0,0,0,0,0};
  for (int i = threadIdx.x; i < T_*2; i += 256) {
    const int e = topi[i]; const float wv = tkwt[i];
#pragma unroll
    for (int k = 0; k < 8; ++k) u[k] += (e == k) ? wv : 0.f;
  }
  __shared__ float red[256];
  float usage[8];
#pragma unroll
  for (int e = 0; e < 8; ++e) {
    red[threadIdx.x] = u[e];
    __syncthreads();
    for (int s = 128; s > 0; s >>= 1) {
      if ((int)threadIdx.x < s) red[threadIdx.x] += red[threadIdx.x + s];
      __syncthreads();
    }
    usage[e] = red[0];
    __syncthreads();
  }
  if (threadIdx.x == 0) {
    float sum = 0;
#pragma unroll
    for (int e = 0; e < 8; ++e) sum += usage[e];
    float Hh = 0;
#pragma unroll
    for (int e = 0; e < 8; ++e) {
      const float p = usage[e] / sum;
      Hh -= p * logf(p + 1e-9f);
    }
    if (first) *aux_out = 0.5f * Hh;
    else *aux_out += 0.5f * Hh;
  }
}

// ---------------- launcher ----------------
extern "C" void kernel_launch(void* const* d_in, const int* in_sizes, int n_in,
                              void* d_out, int out_size, void* d_ws, size_t ws_size,
                              hipStream_t stream) {
  const float* src    = (const float*)d_in[0];
  const float* pos    = (const float*)d_in[1];
  const float* qkv_w  = (const float*)d_in[2];
  const float* qkv_b  = (const float*)d_in[3];
  const float* out_w  = (const float*)d_in[4];
  const float* out_b  = (const float*)d_in[5];
  const float* ln1_w  = (const float*)d_in[6];
  const float* ln1_b  = (const float*)d_in[7];
  const float* ln2_w  = (const float*)d_in[8];
  const float* ln2_b  = (const float*)d_in[9];
  const float* gate_w = (const float*)d_in[10];
  const float* gate_b = (const float*)d_in[11];
  const float* w1     = (const float*)d_in[12];
  const float* b1     = (const float*)d_in[13];
  const float* w2     = (const float*)d_in[14];
  const float* b2     = (const float*)d_in[15];
  float* out = (float*)d_out;

  char* ws = (char*)d_ws;
  size_t off = 0;
  auto alloc = [&](size_t bytes) -> char* {
    char* p = ws + off;
    off = (off + bytes + 255) & ~(size_t)255;
    return p;
  };
  const size_t TD = (size_t)T_ * D_;
  float* x_master = (float*)alloc(TD*4);
  float* ln1_f    = (float*)alloc(TD*4);
  float* moe_out  = (float*)alloc(TD*4);
  _Float16* L1h   = (_Float16*)alloc(TD*2);
  _Float16* L1l   = (_Float16*)alloc(TD*2);
  // dense weight planes (per layer)
  const size_t QW = (size_t)3*D_*D_;
  _Float16* DQh = (_Float16*)alloc(QW*2);
  _Float16* DQl = (_Float16*)alloc(QW*2);
  _Float16* DOh = (_Float16*)alloc((size_t)D_*D_*2);
  _Float16* DOl = (_Float16*)alloc((size_t)D_*D_*2);
  float* scores   = (float*)alloc((size_t)T_*E_*4);
  int*   topi     = (int*)alloc((size_t)T_*2*4);
  float* tkwt     = (float*)alloc((size_t)T_*2*4);
  int*   tkpos    = (int*)alloc((size_t)T_*2*4);
  int*   pairs_tok= (int*)alloc((size_t)TP_*4);
  int*   cnt      = (int*)alloc(E_*4);
  int*   cursor   = (int*)alloc(E_*4);
  int*   nblk     = (int*)alloc(256);
  unsigned char* blk_e = (unsigned char*)alloc(256);
  // union: attn (TD*24) vs moe (H planes + y + w1/w2 planes)
  const size_t attn_sz = TD*24;
  const size_t hrows = (size_t)HALF_BLK * 128;
  const size_t WE = (size_t)E_*FF_*D_;       // elems per-layer w1 (= w2)
  const size_t moe_sz = hrows*FF_*2*2 + (size_t)TP_*D_*4 + WE*2*4;
  char* uni = alloc(attn_sz > moe_sz ? attn_sz : moe_sz);
  // attn-phase views
  _Float16* QKh = (_Float16*)uni;
  _Float16* QKl = (_Float16*)(uni + TD*4);
  _Float16* Vh  = (_Float16*)(uni + TD*8);
  _Float16* Vl  = (_Float16*)(uni + TD*10);
  _Float16* Vth = (_Float16*)(uni + TD*12);
  _Float16* Vtl = (_Float16*)(uni + TD*14);
  _Float16* XPh = (_Float16*)(uni + TD*16);
  _Float16* XPl = (_Float16*)(uni + TD*18);
  _Float16* XFh = (_Float16*)(uni + TD*20);
  _Float16* XFl = (_Float16*)(uni + TD*22);
  _Float16* Oh  = XFh;
  _Float16* Ol  = XFl;
  // moe-phase views
  _Float16* Hh  = (_Float16*)uni;
  _Float16* Hl  = (_Float16*)(uni + hrows*FF_*2);
  float* y_buf  = (float*)(uni + hrows*FF_*4);
  _Float16* W1h = (_Float16*)(uni + hrows*FF_*4 + (size_t)TP_*D_*4);
  _Float16* W1l = W1h + WE;
  _Float16* W2h = W1l + WE;
  _Float16* W2l = W2h + WE;

  for (int l = 0; l < L_; ++l) {
    const float* x_f  = (l == 0) ? src : x_master;
    const float* qkvw = qkv_w + (size_t)l*3*D_*D_;
    const float* qkvb = qkv_b + (size_t)l*3*D_;
    const float* outw = out_w + (size_t)l*D_*D_;
    const float* outb = out_b + (size_t)l*D_;
    const float* w1l  = w1 + (size_t)l*WE;
    const float* b1l  = b1 + (size_t)l*E_*FF_;
    const float* w2l  = w2 + (size_t)l*WE;
    const float* b2l  = b2 + (size_t)l*E_*D_;

    // 0. dense weight planes
    wsplit_kernel<true><<<QW/1024, 256, 0, stream>>>(qkvw, DQh, DQl);
    wsplit_kernel<true><<<D_*D_/1024, 256, 0, stream>>>(outw, DOh, DOl);
    // 1. activation planes
    addpos_kernel<<<TD/1024, 256, 0, stream>>>(x_f, pos, XPh, XPl, XFh, XFl);
    // 2. [Q|K] planes = (x+pos) @ qkv_w[:2D]^T + b
    gemm_qq<3,false,false,false,1><<<dim3(T_/128, 16), 256, 0, stream>>>(
        XPh, XPl, DQh, DQl, qkvb, nullptr, QKh, QKl,
        D_, 2*D_, 0, 0, nullptr, nullptr, nullptr, 0);
    // 3. V planes = x @ qkv_w[2D:]^T + b
    gemm_qq<3,false,false,false,1><<<dim3(T_/128, 8), 256, 0, stream>>>(
        XFh, XFl, DQh + (size_t)2*D_*D_, DQl + (size_t)2*D_*D_, qkvb + 2*D_,
        nullptr, Vh, Vl, D_, D_, 0, 0, nullptr, nullptr, nullptr, 0);
    // 4. V transpose
    vtrans_kernel<<<dim3(16, 128), 256, 0, stream>>>(Vh, Vl, Vth, Vtl);
    // 5. flash attention -> O planes (overwrites XF)
    attn_kernel<<<dim3(16, 128), 256, 0, stream>>>(QKh, QKl, Vth, Vtl, Oh, Ol);
    // 6. proj = O @ out_w^T + b (into moe_out)
    gemm_qq<3,false,false,false,0><<<dim3(T_/128, 8), 256, 0, stream>>>(
        Oh, Ol, DOh, DOl, outb, moe_out, nullptr, nullptr,
        D_, D_, 0, 0, nullptr, nullptr, nullptr, 0);
    // 6b. MoE weight planes (after attn-phase buffers are dead)
    if (l == 0) {
      wsplit_kernel<true><<<WE/1024, 256, 0, stream>>>(w1l, W1h, W1l);
      wsplit_kernel<true><<<WE/1024, 256, 0, stream>>>(w2l, W2h, W2l);
    } else {
      wsplit_kernel<false><<<WE/1024, 256, 0, stream>>>(w1l, W1h, nullptr);
      wsplit_kernel<false><<<WE/1024, 256, 0, stream>>>(w2l, W2h, nullptr);
    }
    // 7. ln1 = LN(x + proj)
    ln_kernel<true><<<T_, 256, 0, stream>>>(x_f, moe_out, ln1_w + (size_t)l*D_,
        ln1_b + (size_t)l*D_, ln1_f, L1h, L1l);
    // 8-11. gate -> top2 -> plan -> fill
    gate_kernel<<<T_/32, 256, 0, stream>>>(ln1_f, gate_w + (size_t)l*E_*D_,
        gate_b + (size_t)l*E_, scores);
    (void)hipMemsetAsync(cnt, 0, E_*4, stream);
    topk_kernel<<<T_/256, 256, 0, stream>>>(scores, topi, tkwt, cnt);
    plan_kernel<<<1, 256, 0, stream>>>(cnt, cursor, nblk, blk_e, pairs_tok);
    fill_kernel<<<T_/256, 256, 0, stream>>>(topi, cursor, pairs_tok, tkpos);
    // 12-13. MoE FFN in two row-block halves
    for (int half = 0; half < 2; ++half) {
      const int mb0 = half * HALF_BLK;
      if (l == 0) {
        gemm_qq<3,true,true,true,1><<<dim3(HALF_BLK, FF_/128), 256, 0, stream>>>(
            L1h, L1l, W1h, W1l, b1l, nullptr, Hh, Hl,
            D_, FF_, (long)FF_*D_, FF_, pairs_tok, nblk, blk_e, mb0);
        gemm_qq<3,false,true,false,0><<<dim3(HALF_BLK, D_/128), 256, 0, stream>>>(
            Hh, Hl, W2h, W2l, b2l, y_buf, nullptr, nullptr,
            FF_, D_, (long)D_*FF_, D_, nullptr, nblk, blk_e, mb0);
      } else {
        gemm_qq<1,true,true,true,2><<<dim3(HALF_BLK, FF_/128), 256, 0, stream>>>(
            L1h, nullptr, W1h, nullptr, b1l, nullptr, Hh, nullptr,
            D_, FF_, (long)FF_*D_, FF_, pairs_tok, nblk, blk_e, mb0);
        gemm_qq<1,false,true,false,0><<<dim3(HALF_BLK, D_/128), 256, 0, stream>>>(
            Hh, nullptr, W2h, nullptr, b2l, y_buf, nullptr, nullptr,
            FF_, D_, (long)D_*FF_, D_, nullptr, nblk, blk_e, mb0);
      }
    }
    // 14. combine
    combine_kernel<<<T_, 256, 0, stream>>>(y_buf, tkpos, tkwt, moe_out);
    // 15. aux
    aux_kernel<<<1, 256, 0, stream>>>(topi, tkwt, out + TD, l == 0 ? 1 : 0);
    // 16. x = LN(ln1 + moe_out)
    float* ln2_dst = (l == L_-1) ? out : x_master;
    ln_kernel<false><<<T_, 256, 0, stream>>>(ln1_f, moe_out, ln2_w + (size_t)l*D_,
        ln2_b + (size_t)l*D_, ln2_dst, nullptr, nullptr);
  }
}